// Round 1
// baseline (8062.125 us; speedup 1.0000x reference)
//
#include <hip/hip_runtime.h>
#include <hip/hip_bf16.h>
#include <math.h>

#define TNODE 256
#define TS 256

__device__ __forceinline__ float sigm(float x) {
    return 1.0f / (1.0f + __expf(-x));
}
__device__ __forceinline__ float tanhfast(float x) {
    float a = fabsf(x);
    float t = __expf(-2.0f * a);
    float r = (1.0f - t) / (1.0f + t);
    return copysignf(r, x);
}

// ---------------------------------------------------------------------------
// prep: transpose weights into ws, compute segment starts via binary search
// ws weight region layout (floats):
//   l0T [64][64]    @ 0      (l0T[k*64+j]  = l0w[j*64+k])
//   l1T [64][64]    @ 4096
//   giT [64][192]   @ 8192   (giT[k*192+j] = gwih[j*64+k])
//   ghT [64][192]   @ 20480
//   liT [128][256]  @ 32768  (liT[k*256+t] = lwih[t*128+k])
//   lhT [64][256]   @ 65536
//   total 81920 floats
// ---------------------------------------------------------------------------
__global__ void prep_kernel(const float* __restrict__ l0w, const float* __restrict__ l1w,
                            const float* __restrict__ gwih, const float* __restrict__ gwhh,
                            const float* __restrict__ lwih, const float* __restrict__ lwhh,
                            const int* __restrict__ batch,
                            float* __restrict__ wT, int* __restrict__ startp,
                            int n_nodes, int n_graphs)
{
    int tid = blockIdx.x * 256 + threadIdx.x;
    float* l0T = wT;
    float* l1T = wT + 4096;
    float* giT = wT + 8192;
    float* ghT = wT + 20480;
    float* liT = wT + 32768;
    float* lhT = wT + 65536;
    if (tid < 4096) {
        int k = tid >> 6, j = tid & 63;
        l0T[k * 64 + j] = l0w[j * 64 + k];
        l1T[k * 64 + j] = l1w[j * 64 + k];
    }
    if (tid < 12288) {
        int k = tid / 192, j = tid % 192;
        giT[tid] = gwih[j * 64 + k];
        ghT[tid] = gwhh[j * 64 + k];
    }
    if (tid < 32768) {
        int k = tid >> 8, t = tid & 255;
        liT[tid] = lwih[t * 128 + k];
    }
    if (tid < 16384) {
        int k = tid >> 8, t = tid & 255;
        lhT[tid] = lwhh[t * 64 + k];
    }
    if (tid <= n_graphs) {
        int lo = 0, hi = n_nodes;
        while (lo < hi) {
            int mid = (lo + hi) >> 1;
            if (batch[mid] < tid) lo = mid + 1; else hi = mid;
        }
        startp[tid] = lo;
    }
}

// ---------------------------------------------------------------------------
// node pipeline: out = 3x(GRU(relu(lin1(.)))) of relu(lin0(x))
// thread = node. Per-thread state vectors in LDS columns [k][tid]:
// every LDS access has fixed row / lane-varying tid -> conflict-free, and
// each thread only touches its own column -> no barriers needed.
// ---------------------------------------------------------------------------
__launch_bounds__(TNODE, 1)
__global__ void node_kernel(const float* __restrict__ x,
                            const float* __restrict__ wT,
                            const float* __restrict__ l0b,
                            const float* __restrict__ l1b,
                            const float* __restrict__ gbih,
                            const float* __restrict__ gbhh,
                            float* __restrict__ outv,
                            int n_nodes)
{
    __shared__ float MB[64 * TNODE];  // x, then m
    __shared__ float HB[64 * TNODE];  // h
    const float* l0T = wT;
    const float* l1T = wT + 4096;
    const float* giT = wT + 8192;
    const float* ghT = wT + 20480;
    const int tid = threadIdx.x;
    const long node = (long)blockIdx.x * TNODE + tid;
    const bool valid = node < (long)n_nodes;
    const long nld = valid ? node : (long)(n_nodes - 1);

    // stage x row -> MB column (per-lane row read, conflict-free LDS writes)
    {
        const float4* xr = (const float4*)(x + nld * 64);
#pragma unroll
        for (int u = 0; u < 16; ++u) {
            float4 v = xr[u];
            MB[(4 * u + 0) * TNODE + tid] = v.x;
            MB[(4 * u + 1) * TNODE + tid] = v.y;
            MB[(4 * u + 2) * TNODE + tid] = v.z;
            MB[(4 * u + 3) * TNODE + tid] = v.w;
        }
    }
    // lin0: HB = relu(W0 x + b0)
#pragma unroll
    for (int jc = 0; jc < 4; ++jc) {
        float acc[16];
#pragma unroll
        for (int jj = 0; jj < 16; ++jj) acc[jj] = l0b[jc * 16 + jj];
        for (int k = 0; k < 64; ++k) {
            float mk = MB[k * TNODE + tid];
#pragma unroll
            for (int jj = 0; jj < 16; ++jj)
                acc[jj] = fmaf(l0T[k * 64 + jc * 16 + jj], mk, acc[jj]);
        }
#pragma unroll
        for (int jj = 0; jj < 16; ++jj)
            HB[(jc * 16 + jj) * TNODE + tid] = fmaxf(acc[jj], 0.0f);
    }

    float hnew[64];
    for (int iter = 0; iter < 3; ++iter) {
        // lin1: MB = relu(W1 h + b1)
#pragma unroll
        for (int jc = 0; jc < 4; ++jc) {
            float acc[16];
#pragma unroll
            for (int jj = 0; jj < 16; ++jj) acc[jj] = l1b[jc * 16 + jj];
            for (int k = 0; k < 64; ++k) {
                float hk = HB[k * TNODE + tid];
#pragma unroll
                for (int jj = 0; jj < 16; ++jj)
                    acc[jj] = fmaf(l1T[k * 64 + jc * 16 + jj], hk, acc[jj]);
            }
#pragma unroll
            for (int jj = 0; jj < 16; ++jj)
                MB[(jc * 16 + jj) * TNODE + tid] = fmaxf(acc[jj], 0.0f);
        }
        // GRU gates (r rows 0..63, z rows 64..127, n rows 128..191)
#pragma unroll
        for (int jc = 0; jc < 4; ++jc) {
            float aIR[16], aHR[16];
#pragma unroll
            for (int jj = 0; jj < 16; ++jj) {
                aIR[jj] = gbih[jc * 16 + jj];
                aHR[jj] = gbhh[jc * 16 + jj];
            }
            for (int k = 0; k < 64; ++k) {
                float mk = MB[k * TNODE + tid];
                float hk = HB[k * TNODE + tid];
#pragma unroll
                for (int jj = 0; jj < 16; ++jj) {
                    aIR[jj] = fmaf(giT[k * 192 + jc * 16 + jj], mk, aIR[jj]);
                    aHR[jj] = fmaf(ghT[k * 192 + jc * 16 + jj], hk, aHR[jj]);
                }
            }
            float rg[16];
#pragma unroll
            for (int jj = 0; jj < 16; ++jj) rg[jj] = sigm(aIR[jj] + aHR[jj]);

            float aIZ[16], aHZ[16];
#pragma unroll
            for (int jj = 0; jj < 16; ++jj) {
                aIZ[jj] = gbih[64 + jc * 16 + jj];
                aHZ[jj] = gbhh[64 + jc * 16 + jj];
            }
            for (int k = 0; k < 64; ++k) {
                float mk = MB[k * TNODE + tid];
                float hk = HB[k * TNODE + tid];
#pragma unroll
                for (int jj = 0; jj < 16; ++jj) {
                    aIZ[jj] = fmaf(giT[k * 192 + 64 + jc * 16 + jj], mk, aIZ[jj]);
                    aHZ[jj] = fmaf(ghT[k * 192 + 64 + jc * 16 + jj], hk, aHZ[jj]);
                }
            }
            float zg[16];
#pragma unroll
            for (int jj = 0; jj < 16; ++jj) zg[jj] = sigm(aIZ[jj] + aHZ[jj]);

            float aIN[16], aHN[16];
#pragma unroll
            for (int jj = 0; jj < 16; ++jj) {
                aIN[jj] = gbih[128 + jc * 16 + jj];
                aHN[jj] = gbhh[128 + jc * 16 + jj];
            }
            for (int k = 0; k < 64; ++k) {
                float mk = MB[k * TNODE + tid];
                float hk = HB[k * TNODE + tid];
#pragma unroll
                for (int jj = 0; jj < 16; ++jj) {
                    aIN[jj] = fmaf(giT[k * 192 + 128 + jc * 16 + jj], mk, aIN[jj]);
                    aHN[jj] = fmaf(ghT[k * 192 + 128 + jc * 16 + jj], hk, aHN[jj]);
                }
            }
#pragma unroll
            for (int jj = 0; jj < 16; ++jj) {
                float ng = tanhfast(aIN[jj] + rg[jj] * aHN[jj]);
                float hold = HB[(jc * 16 + jj) * TNODE + tid];
                hnew[jc * 16 + jj] = (1.0f - zg[jj]) * ng + zg[jj] * hold;
            }
        }
        if (iter < 2) {
#pragma unroll
            for (int j = 0; j < 64; ++j) HB[j * TNODE + tid] = hnew[j];
        }
    }
    if (valid) {
        float4* orow = (float4*)(outv + node * 64);
#pragma unroll
        for (int u = 0; u < 16; ++u) {
            float4 v;
            v.x = hnew[4 * u + 0]; v.y = hnew[4 * u + 1];
            v.z = hnew[4 * u + 2]; v.w = hnew[4 * u + 3];
            orow[u] = v;
        }
    }
}

// ---------------------------------------------------------------------------
// Set2Set (3 steps) + head; one block per graph (segments contiguous: batch
// is sorted). Node features read from global (L2-resident working set).
// ---------------------------------------------------------------------------
__device__ __forceinline__ float blk_max(float v, float* redm, int t) {
#pragma unroll
    for (int o = 32; o > 0; o >>= 1) v = fmaxf(v, __shfl_xor(v, o));
    __syncthreads();
    if ((t & 63) == 0) redm[t >> 6] = v;
    __syncthreads();
    return fmaxf(fmaxf(redm[0], redm[1]), fmaxf(redm[2], redm[3]));
}
__device__ __forceinline__ float blk_sum(float v, float* redm, int t) {
#pragma unroll
    for (int o = 32; o > 0; o >>= 1) v += __shfl_xor(v, o);
    __syncthreads();
    if ((t & 63) == 0) redm[t >> 6] = v;
    __syncthreads();
    return (redm[0] + redm[1]) + (redm[2] + redm[3]);
}
__device__ __forceinline__ float node_dot(const float* __restrict__ outv, long row,
                                          const float* q) {
    const float4* rp = (const float4*)(outv + row * 64);
    float e = 0.0f;
#pragma unroll
    for (int u = 0; u < 16; ++u) {
        float4 v = rp[u];
        e = fmaf(v.x, q[4 * u + 0], e);
        e = fmaf(v.y, q[4 * u + 1], e);
        e = fmaf(v.z, q[4 * u + 2], e);
        e = fmaf(v.w, q[4 * u + 3], e);
    }
    return e;
}

__global__ void s2s_kernel(const float* __restrict__ outv,
                           const int* __restrict__ startp,
                           const float* __restrict__ wT,
                           const float* __restrict__ lbih, const float* __restrict__ lbhh,
                           const float* __restrict__ l2w, const float* __restrict__ l2b,
                           const float* __restrict__ l3w, const float* __restrict__ l3b,
                           float* __restrict__ yout)
{
    __shared__ float qstarS[128];
    __shared__ float hlS[64];
    __shared__ float clS[64];
    __shared__ float g4[256];
    __shared__ float red[256];
    __shared__ float eS[512];
    __shared__ float redm[4];

    const float* liT = wT + 32768;
    const float* lhT = wT + 65536;
    const int g = blockIdx.x;
    const int t = threadIdx.x;
    const int s0 = startp[g];
    const int cnt = startp[g + 1] - s0;

    if (t < 128) qstarS[t] = 0.0f;
    if (t < 64) { hlS[t] = 0.0f; clS[t] = 0.0f; }
    __syncthreads();

    for (int step = 0; step < 3; ++step) {
        // LSTM gates: thread t computes gate row t (coalesced transposed weights)
        float acc = lbih[t] + lbhh[t];
        for (int k = 0; k < 128; ++k) acc = fmaf(liT[k * 256 + t], qstarS[k], acc);
        for (int k = 0; k < 64; ++k)  acc = fmaf(lhT[k * 256 + t], hlS[k], acc);
        g4[t] = acc;
        __syncthreads();
        if (t < 64) {
            float c = sigm(g4[64 + t]) * clS[t] + sigm(g4[t]) * tanhfast(g4[128 + t]);
            clS[t] = c;
            hlS[t] = sigm(g4[192 + t]) * tanhfast(c);  // q = hl
        }
        __syncthreads();

        // pass 1: e_n and segment max
        float lmax = -INFINITY;
        for (int n = t; n < cnt; n += TS) {
            float e = node_dot(outv, (long)(s0 + n), hlS);
            lmax = fmaxf(lmax, e);
            if (n < 512) eS[n] = e;
        }
        float mval = blk_max(lmax, redm, t);

        // pass 2: sum of exp (store exp into eS)
        float lsum = 0.0f;
        for (int n = t; n < cnt; n += TS) {
            float e = (n < 512) ? eS[n] : node_dot(outv, (long)(s0 + n), hlS);
            float ex = __expf(e - mval);
            lsum += ex;
            if (n < 512) eS[n] = ex;
        }
        float sval = blk_sum(lsum, redm, t);  // barriers inside make eS visible

        // pass 3: r_d = sum_n exp_n * out[n][d]
        float racc = 0.0f;
        {
            const int d = t & 63;
            const int q4 = t >> 6;
            const int nl = cnt < 512 ? cnt : 512;
            for (int n = q4; n < nl; n += 4)
                racc = fmaf(eS[n], outv[(long)(s0 + n) * 64 + d], racc);
            if (t < 64) {  // generic (never-hot) overflow path
                for (int n = 512; n < cnt; ++n) {
                    float e = outv[(long)(s0 + n) * 64 + t] * hlS[t];
#pragma unroll
                    for (int o = 32; o > 0; o >>= 1) e += __shfl_xor(e, o);
                    float ex = __expf(e - mval);
                    racc = fmaf(ex, outv[(long)(s0 + n) * 64 + t], racc);
                }
            }
        }
        red[t] = racc;
        __syncthreads();
        if (t < 64) {
            float r = (red[t] + red[64 + t]) + (red[128 + t] + red[192 + t]);
            qstarS[t] = hlS[t];
            qstarS[64 + t] = r / (sval + 1e-16f);
        }
        __syncthreads();
    }

    // head: y = relu(lin2(qstar)); out = lin3(y)
    if (t < 64) {
        float acc = l2b[t];
        for (int k = 0; k < 128; ++k) acc = fmaf(l2w[t * 128 + k], qstarS[k], acc);
        g4[t] = fmaxf(acc, 0.0f);
    }
    __syncthreads();
    if (t < 64) {
        float p = l3w[t] * g4[t];
#pragma unroll
        for (int o = 32; o > 0; o >>= 1) p += __shfl_xor(p, o);
        if (t == 0) yout[g] = p + l3b[0];
    }
}

// ---------------------------------------------------------------------------
extern "C" void kernel_launch(void* const* d_in, const int* in_sizes, int n_in,
                              void* d_out, int out_size, void* d_ws, size_t ws_size,
                              hipStream_t stream)
{
    const float* x     = (const float*)d_in[0];
    const int*   batch = (const int*)d_in[1];
    const float* l0w   = (const float*)d_in[2];
    const float* l0b   = (const float*)d_in[3];
    const float* l1w   = (const float*)d_in[4];
    const float* l1b   = (const float*)d_in[5];
    const float* gwih  = (const float*)d_in[6];
    const float* gwhh  = (const float*)d_in[7];
    const float* gbih  = (const float*)d_in[8];
    const float* gbhh  = (const float*)d_in[9];
    const float* lwih  = (const float*)d_in[10];
    const float* lwhh  = (const float*)d_in[11];
    const float* lbih  = (const float*)d_in[12];
    const float* lbhh  = (const float*)d_in[13];
    const float* l2w   = (const float*)d_in[14];
    const float* l2b   = (const float*)d_in[15];
    const float* l3w   = (const float*)d_in[16];
    const float* l3b   = (const float*)d_in[17];

    const int n_nodes  = in_sizes[1];   // batch array length
    const int n_graphs = out_size;      // one scalar per graph

    float* wsf    = (float*)d_ws;
    float* outv   = wsf;                                  // [n_nodes*64] node features
    float* wTrans = wsf + (size_t)n_nodes * 64;           // 81920 floats of transposed weights
    int*   startp = (int*)(wTrans + 81920);               // [n_graphs+1]

    prep_kernel<<<128, 256, 0, stream>>>(l0w, l1w, gwih, gwhh, lwih, lwhh,
                                         batch, wTrans, startp, n_nodes, n_graphs);
    node_kernel<<<(n_nodes + TNODE - 1) / TNODE, TNODE, 0, stream>>>(
        x, wTrans, l0b, l1b, gbih, gbhh, outv, n_nodes);
    s2s_kernel<<<n_graphs, TS, 0, stream>>>(outv, startp, wTrans,
                                            lbih, lbhh, l2w, l2b, l3w, l3b,
                                            (float*)d_out);
}

// Round 2
// 1296.498 us; speedup vs baseline: 6.2184x; 6.2184x over previous
//
#include <hip/hip_runtime.h>
#include <hip/hip_bf16.h>
#include <math.h>

#define TS 256
#define TILES 8
#define MBLK 128

typedef __attribute__((ext_vector_type(8))) short bf8;
typedef __attribute__((ext_vector_type(4))) float f32x4;

#define MFMA(a, b, c) __builtin_amdgcn_mfma_f32_16x16x32_bf16(a, b, c, 0, 0, 0)

__device__ __forceinline__ float fast_rcp(float x) { return __builtin_amdgcn_rcpf(x); }
__device__ __forceinline__ float sigm(float x) { return fast_rcp(1.0f + __expf(-x)); }
__device__ __forceinline__ float tanh2(float x) { return fmaf(2.0f, fast_rcp(1.0f + __expf(-2.0f * x)), -1.0f); }

__device__ __forceinline__ unsigned short f2bf(float v) {
    union { __hip_bfloat16 b; unsigned short u; } cv;
    cv.b = __float2bfloat16(v);
    return cv.u;
}
__device__ __forceinline__ float bf2f(unsigned short u) {
    union { unsigned short u; __hip_bfloat16 b; } cv;
    cv.u = u;
    return __bfloat162float(cv.b);
}

// ---------------------------------------------------------------------------
// prep: build (a) split-bf16 B-fragments of the node-pipeline weights,
// (b) f32 transposes of the LSTM weights for s2s, (c) segment starts.
//
// B-frag layout (mfma_f32_16x16x32_bf16): frag f = ((jt*2+ks)*64+lane)*8+e
//   j = jt_local*16 + (lane&15), k = ks*32 + (lane>>4)*8 + e, value W[j][k]
// jt global bases: l0 @0(4 tiles), l1 @4(4), gi @8(12), gh @20(12) -> 32 tiles
// ---------------------------------------------------------------------------
__global__ void prep_kernel(const float* __restrict__ l0w, const float* __restrict__ l1w,
                            const float* __restrict__ gwih, const float* __restrict__ gwhh,
                            const float* __restrict__ lwih, const float* __restrict__ lwhh,
                            const int* __restrict__ batch,
                            unsigned short* __restrict__ whi, unsigned short* __restrict__ wlo,
                            float* __restrict__ liT, float* __restrict__ lhT,
                            int* __restrict__ startp,
                            int n_nodes, int n_graphs)
{
    int tid = blockIdx.x * 256 + threadIdx.x;
    if (tid < 32768) {
        int e = tid & 7, lane = (tid >> 3) & 63, ks = (tid >> 9) & 1, jt = tid >> 10;
        const float* W; int jl;
        if (jt < 4)       { W = l0w;  jl = jt; }
        else if (jt < 8)  { W = l1w;  jl = jt - 4; }
        else if (jt < 20) { W = gwih; jl = jt - 8; }
        else              { W = gwhh; jl = jt - 20; }
        int j = jl * 16 + (lane & 15);
        int k = ks * 32 + (lane >> 4) * 8 + e;
        float v = W[j * 64 + k];
        unsigned short hi = f2bf(v);
        whi[tid] = hi;
        wlo[tid] = f2bf(v - bf2f(hi));
    }
    if (tid < 32768) liT[tid] = lwih[(tid & 255) * 128 + (tid >> 8)];
    if (tid < 16384) lhT[tid] = lwhh[(tid & 255) * 64 + (tid >> 8)];
    if (tid <= n_graphs) {
        int lo = 0, hi = n_nodes;
        while (lo < hi) {
            int mid = (lo + hi) >> 1;
            if (batch[mid] < tid) lo = mid + 1; else hi = mid;
        }
        startp[tid] = lo;
    }
}

// ---------------------------------------------------------------------------
// node pipeline via split-bf16 MFMA. Block = 4 waves x 128 nodes.
// Wave w owns output columns [16w,16w+16) of every layer (column-parallel);
// GRU elementwise is column-local so no cross-wave reduction.
// Activations in LDS as A-frag-linear bf16 hi/lo (lane-contiguous 16B ->
// conflict-free ds_read_b128). h additionally carried in C-layout registers.
// ---------------------------------------------------------------------------
__launch_bounds__(256, 2)
__global__ void node_kernel(const float* __restrict__ x,
                            const unsigned short* __restrict__ whi,
                            const unsigned short* __restrict__ wlo,
                            const float* __restrict__ l0b, const float* __restrict__ l1b,
                            const float* __restrict__ gbih, const float* __restrict__ gbhh,
                            float* __restrict__ outv, int n_nodes)
{
    __shared__ unsigned short MHI[8192], MLO[8192], HHI[8192], HLO[8192];
    const int tid = threadIdx.x;
    const int w = tid >> 6, lane = tid & 63, c = lane & 15, g = lane >> 4;
    const long node0 = (long)blockIdx.x * MBLK;
    const int j = w * 16 + c;

    const float bR  = gbih[j] + gbhh[j];
    const float bZ  = gbih[64 + j] + gbhh[64 + j];
    const float bNI = gbih[128 + j];
    const float bNH = gbhh[128 + j];
    const float bL1 = l1b[j];
    const float bL0 = l0b[j];

    // elementwise-write offset: element (row r, k=j) of a tile's frag buffer
    const int koff = ((j >> 5) * 512) + (((j >> 3) & 3) * 128) + (j & 7);

    const bf8* WH = (const bf8*)whi;
    const bf8* WL = (const bf8*)wlo;
#define LF(name, jt) \
    bf8 name##h0 = WH[((jt) * 2 + 0) * 64 + lane], name##h1 = WH[((jt) * 2 + 1) * 64 + lane], \
        name##l0 = WL[((jt) * 2 + 0) * 64 + lane], name##l1 = WL[((jt) * 2 + 1) * 64 + lane];
    LF(w0, w)
    LF(w1, 4 + w)
    LF(gir, 8 + w)  LF(giz, 12 + w)  LF(gin, 16 + w)
    LF(ghr, 20 + w) LF(ghz, 24 + w) LF(ghn, 28 + w)
#undef LF

    float hc[TILES][4];

    // ---- lin0: h = relu(W0 x + b0), x A-frags straight from global ----
#pragma unroll
    for (int t = 0; t < TILES; ++t) {
        long nd = node0 + t * 16 + c;
        if (nd >= n_nodes) nd = n_nodes - 1;
        const float* xp = x + nd * 64 + g * 8;
        float va[8], vb[8];
        {
            float4 u0 = *(const float4*)xp;
            float4 u1 = *(const float4*)(xp + 4);
            float4 u2 = *(const float4*)(xp + 32);
            float4 u3 = *(const float4*)(xp + 36);
            va[0] = u0.x; va[1] = u0.y; va[2] = u0.z; va[3] = u0.w;
            va[4] = u1.x; va[5] = u1.y; va[6] = u1.z; va[7] = u1.w;
            vb[0] = u2.x; vb[1] = u2.y; vb[2] = u2.z; vb[3] = u2.w;
            vb[4] = u3.x; vb[5] = u3.y; vb[6] = u3.z; vb[7] = u3.w;
        }
        bf8 xh0, xl0, xh1, xl1;
#pragma unroll
        for (int e = 0; e < 8; ++e) {
            unsigned short h0 = f2bf(va[e]);
            xh0[e] = (short)h0; xl0[e] = (short)f2bf(va[e] - bf2f(h0));
            unsigned short h1 = f2bf(vb[e]);
            xh1[e] = (short)h1; xl1[e] = (short)f2bf(vb[e] - bf2f(h1));
        }
        f32x4 acc = {bL0, bL0, bL0, bL0};
        acc = MFMA(xh0, w0h0, acc); acc = MFMA(xl0, w0h0, acc); acc = MFMA(xh0, w0l0, acc);
        acc = MFMA(xh1, w0h1, acc); acc = MFMA(xl1, w0h1, acc); acc = MFMA(xh1, w0l1, acc);
#pragma unroll
        for (int p = 0; p < 4; ++p) {
            float hv = fmaxf(acc[p], 0.0f);
            hc[t][p] = hv;
            int r = g * 4 + p;
            unsigned short hi = f2bf(hv);
            HHI[t * 1024 + koff + r * 8] = hi;
            HLO[t * 1024 + koff + r * 8] = f2bf(hv - bf2f(hi));
        }
    }
    __syncthreads();

    for (int iter = 0; iter < 3; ++iter) {
        // ---- lin1: m = relu(W1 h + b1) ----
#pragma unroll
        for (int t = 0; t < TILES; ++t) {
            const bf8* hh = (const bf8*)&HHI[t * 1024];
            const bf8* hl = (const bf8*)&HLO[t * 1024];
            bf8 ah0 = hh[lane], ah1 = hh[64 + lane];
            bf8 al0 = hl[lane], al1 = hl[64 + lane];
            f32x4 acc = {bL1, bL1, bL1, bL1};
            acc = MFMA(ah0, w1h0, acc); acc = MFMA(al0, w1h0, acc); acc = MFMA(ah0, w1l0, acc);
            acc = MFMA(ah1, w1h1, acc); acc = MFMA(al1, w1h1, acc); acc = MFMA(ah1, w1l1, acc);
#pragma unroll
            for (int p = 0; p < 4; ++p) {
                float mv = fmaxf(acc[p], 0.0f);
                int r = g * 4 + p;
                unsigned short hi = f2bf(mv);
                MHI[t * 1024 + koff + r * 8] = hi;
                MLO[t * 1024 + koff + r * 8] = f2bf(mv - bf2f(hi));
            }
        }
        __syncthreads();

        // ---- GRU gates (reads m,h frags; h update kept in registers) ----
#pragma unroll
        for (int t = 0; t < TILES; ++t) {
            const bf8* mh = (const bf8*)&MHI[t * 1024];
            const bf8* ml = (const bf8*)&MLO[t * 1024];
            const bf8* hh = (const bf8*)&HHI[t * 1024];
            const bf8* hl = (const bf8*)&HLO[t * 1024];
            bf8 amh0 = mh[lane], amh1 = mh[64 + lane];
            bf8 aml0 = ml[lane], aml1 = ml[64 + lane];
            bf8 ahh0 = hh[lane], ahh1 = hh[64 + lane];
            bf8 ahl0 = hl[lane], ahl1 = hl[64 + lane];

            f32x4 aR  = {bR, bR, bR, bR};
            f32x4 aZ  = {bZ, bZ, bZ, bZ};
            f32x4 aNI = {bNI, bNI, bNI, bNI};
            f32x4 aNH = {bNH, bNH, bNH, bNH};

            aR = MFMA(amh0, girh0, aR); aR = MFMA(aml0, girh0, aR); aR = MFMA(amh0, girl0, aR);
            aR = MFMA(amh1, girh1, aR); aR = MFMA(aml1, girh1, aR); aR = MFMA(amh1, girl1, aR);
            aR = MFMA(ahh0, ghrh0, aR); aR = MFMA(ahl0, ghrh0, aR); aR = MFMA(ahh0, ghrl0, aR);
            aR = MFMA(ahh1, ghrh1, aR); aR = MFMA(ahl1, ghrh1, aR); aR = MFMA(ahh1, ghrl1, aR);

            aZ = MFMA(amh0, gizh0, aZ); aZ = MFMA(aml0, gizh0, aZ); aZ = MFMA(amh0, gizl0, aZ);
            aZ = MFMA(amh1, gizh1, aZ); aZ = MFMA(aml1, gizh1, aZ); aZ = MFMA(amh1, gizl1, aZ);
            aZ = MFMA(ahh0, ghzh0, aZ); aZ = MFMA(ahl0, ghzh0, aZ); aZ = MFMA(ahh0, ghzl0, aZ);
            aZ = MFMA(ahh1, ghzh1, aZ); aZ = MFMA(ahl1, ghzh1, aZ); aZ = MFMA(ahh1, ghzl1, aZ);

            aNI = MFMA(amh0, ginh0, aNI); aNI = MFMA(aml0, ginh0, aNI); aNI = MFMA(amh0, ginl0, aNI);
            aNI = MFMA(amh1, ginh1, aNI); aNI = MFMA(aml1, ginh1, aNI); aNI = MFMA(amh1, ginl1, aNI);

            aNH = MFMA(ahh0, ghnh0, aNH); aNH = MFMA(ahl0, ghnh0, aNH); aNH = MFMA(ahh0, ghnl0, aNH);
            aNH = MFMA(ahh1, ghnh1, aNH); aNH = MFMA(ahl1, ghnh1, aNH); aNH = MFMA(ahh1, ghnl1, aNH);

#pragma unroll
            for (int p = 0; p < 4; ++p) {
                float rg = sigm(aR[p]);
                float zg = sigm(aZ[p]);
                float ng = tanh2(aNI[p] + rg * aNH[p]);
                hc[t][p] = (1.0f - zg) * ng + zg * hc[t][p];
            }
        }

        if (iter < 2) {
            __syncthreads();   // all gate-phase h reads done
#pragma unroll
            for (int t = 0; t < TILES; ++t)
#pragma unroll
                for (int p = 0; p < 4; ++p) {
                    int r = g * 4 + p;
                    unsigned short hi = f2bf(hc[t][p]);
                    HHI[t * 1024 + koff + r * 8] = hi;
                    HLO[t * 1024 + koff + r * 8] = f2bf(hc[t][p] - bf2f(hi));
                }
            __syncthreads();   // h visible before next lin1
        }
    }

    // ---- store out (f32) ----
#pragma unroll
    for (int t = 0; t < TILES; ++t)
#pragma unroll
        for (int p = 0; p < 4; ++p) {
            long nd = node0 + t * 16 + g * 4 + p;
            if (nd < n_nodes) outv[nd * 64 + j] = hc[t][p];
        }
}

// ---------------------------------------------------------------------------
// Set2Set (3 steps) + head; one block per graph (batch sorted -> contiguous).
// ---------------------------------------------------------------------------
__device__ __forceinline__ float blk_max(float v, float* redm, int t) {
#pragma unroll
    for (int o = 32; o > 0; o >>= 1) v = fmaxf(v, __shfl_xor(v, o));
    __syncthreads();
    if ((t & 63) == 0) redm[t >> 6] = v;
    __syncthreads();
    return fmaxf(fmaxf(redm[0], redm[1]), fmaxf(redm[2], redm[3]));
}
__device__ __forceinline__ float blk_sum(float v, float* redm, int t) {
#pragma unroll
    for (int o = 32; o > 0; o >>= 1) v += __shfl_xor(v, o);
    __syncthreads();
    if ((t & 63) == 0) redm[t >> 6] = v;
    __syncthreads();
    return (redm[0] + redm[1]) + (redm[2] + redm[3]);
}
__device__ __forceinline__ float node_dot(const float* __restrict__ outv, long row,
                                          const float* q) {
    const float4* rp = (const float4*)(outv + row * 64);
    float e = 0.0f;
#pragma unroll
    for (int u = 0; u < 16; ++u) {
        float4 v = rp[u];
        e = fmaf(v.x, q[4 * u + 0], e);
        e = fmaf(v.y, q[4 * u + 1], e);
        e = fmaf(v.z, q[4 * u + 2], e);
        e = fmaf(v.w, q[4 * u + 3], e);
    }
    return e;
}

__global__ void s2s_kernel(const float* __restrict__ outv,
                           const int* __restrict__ startp,
                           const float* __restrict__ liT, const float* __restrict__ lhT,
                           const float* __restrict__ lbih, const float* __restrict__ lbhh,
                           const float* __restrict__ l2w, const float* __restrict__ l2b,
                           const float* __restrict__ l3w, const float* __restrict__ l3b,
                           float* __restrict__ yout)
{
    __shared__ float qstarS[128];
    __shared__ float hlS[64];
    __shared__ float clS[64];
    __shared__ float g4[256];
    __shared__ float red[256];
    __shared__ float eS[512];
    __shared__ float redm[4];

    const int g = blockIdx.x;
    const int t = threadIdx.x;
    const int s0 = startp[g];
    const int cnt = startp[g + 1] - s0;

    if (t < 128) qstarS[t] = 0.0f;
    if (t < 64) { hlS[t] = 0.0f; clS[t] = 0.0f; }
    __syncthreads();

    for (int step = 0; step < 3; ++step) {
        float acc = lbih[t] + lbhh[t];
        for (int k = 0; k < 128; ++k) acc = fmaf(liT[k * 256 + t], qstarS[k], acc);
        for (int k = 0; k < 64; ++k)  acc = fmaf(lhT[k * 256 + t], hlS[k], acc);
        g4[t] = acc;
        __syncthreads();
        if (t < 64) {
            float c = sigm(g4[64 + t]) * clS[t] + sigm(g4[t]) * tanh2(g4[128 + t]);
            clS[t] = c;
            hlS[t] = sigm(g4[192 + t]) * tanh2(c);  // q = hl
        }
        __syncthreads();

        float lmax = -INFINITY;
        for (int n = t; n < cnt; n += TS) {
            float e = node_dot(outv, (long)(s0 + n), hlS);
            lmax = fmaxf(lmax, e);
            if (n < 512) eS[n] = e;
        }
        float mval = blk_max(lmax, redm, t);

        float lsum = 0.0f;
        for (int n = t; n < cnt; n += TS) {
            float e = (n < 512) ? eS[n] : node_dot(outv, (long)(s0 + n), hlS);
            float ex = __expf(e - mval);
            lsum += ex;
            if (n < 512) eS[n] = ex;
        }
        float sval = blk_sum(lsum, redm, t);

        float racc = 0.0f;
        {
            const int d = t & 63;
            const int q4 = t >> 6;
            const int nl = cnt < 512 ? cnt : 512;
            for (int n = q4; n < nl; n += 4)
                racc = fmaf(eS[n], outv[(long)(s0 + n) * 64 + d], racc);
            if (t < 64) {
                for (int n = 512; n < cnt; ++n) {
                    float e = outv[(long)(s0 + n) * 64 + t] * hlS[t];
#pragma unroll
                    for (int o = 32; o > 0; o >>= 1) e += __shfl_xor(e, o);
                    float ex = __expf(e - mval);
                    racc = fmaf(ex, outv[(long)(s0 + n) * 64 + t], racc);
                }
            }
        }
        red[t] = racc;
        __syncthreads();
        if (t < 64) {
            float r = (red[t] + red[64 + t]) + (red[128 + t] + red[192 + t]);
            qstarS[t] = hlS[t];
            qstarS[64 + t] = r / (sval + 1e-16f);
        }
        __syncthreads();
    }

    if (t < 64) {
        float acc = l2b[t];
        for (int k = 0; k < 128; ++k) acc = fmaf(l2w[t * 128 + k], qstarS[k], acc);
        g4[t] = fmaxf(acc, 0.0f);
    }
    __syncthreads();
    if (t < 64) {
        float p = l3w[t] * g4[t];
#pragma unroll
        for (int o = 32; o > 0; o >>= 1) p += __shfl_xor(p, o);
        if (t == 0) yout[g] = p + l3b[0];
    }
}

// ---------------------------------------------------------------------------
extern "C" void kernel_launch(void* const* d_in, const int* in_sizes, int n_in,
                              void* d_out, int out_size, void* d_ws, size_t ws_size,
                              hipStream_t stream)
{
    const float* x     = (const float*)d_in[0];
    const int*   batch = (const int*)d_in[1];
    const float* l0w   = (const float*)d_in[2];
    const float* l0b   = (const float*)d_in[3];
    const float* l1w   = (const float*)d_in[4];
    const float* l1b   = (const float*)d_in[5];
    const float* gwih  = (const float*)d_in[6];
    const float* gwhh  = (const float*)d_in[7];
    const float* gbih  = (const float*)d_in[8];
    const float* gbhh  = (const float*)d_in[9];
    const float* lwih  = (const float*)d_in[10];
    const float* lwhh  = (const float*)d_in[11];
    const float* lbih  = (const float*)d_in[12];
    const float* lbhh  = (const float*)d_in[13];
    const float* l2w   = (const float*)d_in[14];
    const float* l2b   = (const float*)d_in[15];
    const float* l3w   = (const float*)d_in[16];
    const float* l3b   = (const float*)d_in[17];

    const int n_nodes  = in_sizes[1];
    const int n_graphs = out_size;

    float* wsf = (float*)d_ws;
    float* outv = wsf;                                    // n_nodes*64 f32
    float* liT  = wsf + (size_t)n_nodes * 64;             // 32768 f32
    float* lhT  = liT + 32768;                            // 16384 f32
    unsigned short* whi = (unsigned short*)(lhT + 16384); // 32768 u16
    unsigned short* wlo = whi + 32768;                    // 32768 u16
    int* startp = (int*)(wlo + 32768);                    // n_graphs+1

    prep_kernel<<<128, 256, 0, stream>>>(l0w, l1w, gwih, gwhh, lwih, lwhh, batch,
                                         whi, wlo, liT, lhT, startp, n_nodes, n_graphs);
    node_kernel<<<(n_nodes + MBLK - 1) / MBLK, 256, 0, stream>>>(
        x, whi, wlo, l0b, l1b, gbih, gbhh, outv, n_nodes);
    s2s_kernel<<<n_graphs, TS, 0, stream>>>(outv, startp, liT, lhT,
                                            lbih, lbhh, l2w, l2b, l3w, l3b,
                                            (float*)d_out);
}